// Round 1
// baseline (62.845 us; speedup 1.0000x reference)
//
#include <hip/hip_runtime.h>
#include <math.h>

#define TWO_PI_F 6.2831853071795864769f

__device__ __forceinline__ float gelu_f(float v) {
    // exact gelu: 0.5*x*(1+erf(x/sqrt(2)))
    return 0.5f * v * (1.0f + erff(v * 0.7071067811865476f));
}

// ---------------- pass 1: global sums of |lo_n| over the whole batch ----------------
__global__ __launch_bounds__(256) void k_pass1(
    const float* __restrict__ x,
    const float* __restrict__ W_in, const float* __restrict__ b_in,
    const float* __restrict__ r_tf,
    float* __restrict__ partials, int B)
{
    // uniform weights -> registers (hoisted out of the row loop)
    float w[24], bi[4], tf[32];
#pragma unroll
    for (int i = 0; i < 24; ++i) w[i] = W_in[i];
#pragma unroll
    for (int i = 0; i < 4; ++i) bi[i] = b_in[i];
#pragma unroll
    for (int i = 0; i < 32; ++i) tf[i] = r_tf[i];

    float s0 = 0.f, s1 = 0.f;
    const int stride = gridDim.x * blockDim.x;
    for (int i = blockIdx.x * blockDim.x + threadIdx.x; i < B; i += stride) {
        const float2* xp = (const float2*)(x + (size_t)i * 6);
        float2 p0 = xp[0], p1 = xp[1], p2 = xp[2];
        float xv[6] = {p0.x, p0.y, p1.x, p1.y, p2.x, p2.y};
        float xr[4];
#pragma unroll
        for (int j = 0; j < 4; ++j) {
            float a = bi[j];
#pragma unroll
            for (int k = 0; k < 6; ++k) a = fmaf(w[j*6+k], xv[k], a);
            xr[j] = gelu_f(a);
        }
#pragma unroll
        for (int j = 0; j < 4; ++j) {
            float l0 = 0.f, l1 = 0.f;
#pragma unroll
            for (int k = 0; k < 4; ++k) {
                l0 = fmaf(tf[j*4+k],      xr[k], l0);
                l1 = fmaf(tf[16 + j*4+k], xr[k], l1);
            }
            s0 += fabsf(l0);
            s1 += fabsf(l1);
        }
    }
#pragma unroll
    for (int off = 32; off > 0; off >>= 1) {
        s0 += __shfl_down(s0, off);
        s1 += __shfl_down(s1, off);
    }
    __shared__ float sm[8];
    const int wid = threadIdx.x >> 6;
    if ((threadIdx.x & 63) == 0) { sm[wid*2] = s0; sm[wid*2+1] = s1; }
    __syncthreads();
    if (threadIdx.x == 0) {
        float t0 = 0.f, t1 = 0.f;
        const int nw = (int)(blockDim.x >> 6);
        for (int k2 = 0; k2 < nw; ++k2) { t0 += sm[k2*2]; t1 += sm[k2*2+1]; }
        partials[(size_t)blockIdx.x * 2]     = t0;
        partials[(size_t)blockIdx.x * 2 + 1] = t1;
    }
}

// ---------------- mid: finalize sums; fold the whole internal path into W_eff/b_eff ----
// cst layout (floats): [0]=c0 [1]=c1 [2]=sr  [8..39]=W_eff(8x4) [40..47]=b_eff(8)
__global__ __launch_bounds__(256) void k_mid(
    const float* __restrict__ partials, int nb, int B,
    const float* __restrict__ i_w,  const float* __restrict__ i_b,
    const float* __restrict__ i_tf, const float* __restrict__ i_tc,
    const float* __restrict__ W_ri, const float* __restrict__ b_ri,
    const float* __restrict__ W_ir, const float* __restrict__ b_ir,
    const float* __restrict__ flow_gate, const float* __restrict__ mem,
    const float* __restrict__ W_o1, const float* __restrict__ b_o1,
    const float* __restrict__ r_tc,
    float* __restrict__ cst)
{
    __shared__ float red[8];
    __shared__ float hc[16];
    __shared__ float cv[4];

    // --- reduce block partials (deterministic) ---
    float s0 = 0.f, s1 = 0.f;
    for (int k = threadIdx.x; k < nb; k += blockDim.x) {
        s0 += partials[(size_t)k*2];
        s1 += partials[(size_t)k*2 + 1];
    }
#pragma unroll
    for (int off = 32; off > 0; off >>= 1) { s0 += __shfl_down(s0, off); s1 += __shfl_down(s1, off); }
    const int wid = threadIdx.x >> 6;
    if ((threadIdx.x & 63) == 0) { red[wid*2] = s0; red[wid*2+1] = s1; }
    __syncthreads();
    if (threadIdx.x == 0) {
        float t0 = 0.f, t1 = 0.f;
        for (int k2 = 0; k2 < 4; ++k2) { t0 += red[k2*2]; t1 += red[k2*2+1]; }
        const float m0 = t0 / (4.0f * (float)B);
        const float m1 = t1 / (4.0f * (float)B);
        cst[0] = TWO_PI_F * 1.0f / (m0 + 1e-8f);
        cst[1] = TWO_PI_F * 2.0f / (m1 + 1e-8f);
        cst[2] = 1.0f / (1.0f + expf(-r_tc[0]));   // sigmoid(r_tc)
    }

    // --- h_i constant vector (internal torsion field on broadcast mem), wave 0 ---
    if (threadIdx.x < 64) {
        const int j = threadIdx.x & 15;   // all 64 lanes active -> shuffles valid
        float base = i_b[j];
#pragma unroll
        for (int k = 0; k < 16; ++k) base = fmaf(i_w[j*16 + k], mem[k], base);
        float corr = 0.f;
#pragma unroll
        for (int n = 0; n < 3; ++n) {
            float lo = 0.f;
#pragma unroll
            for (int k = 0; k < 16; ++k) lo = fmaf(i_tf[n*256 + j*16 + k], mem[k], lo);
            float a = fabsf(lo);
            a += __shfl_xor(a, 1); a += __shfl_xor(a, 2); a += __shfl_xor(a, 4); a += __shfl_xor(a, 8);
            const float mean = a * (1.0f/16.0f);
            const float phase = TWO_PI_F * (float)(n+1) * lo / (mean + 1e-8f);
            corr = fmaf(sinf(phase), lo / (float)(n+1), corr);
        }
        const float sc = 1.0f / (1.0f + expf(-i_tc[0]));
        const float t = fmaf(sc, corr, base);
        float mu = t;
        mu += __shfl_xor(mu, 1); mu += __shfl_xor(mu, 2); mu += __shfl_xor(mu, 4); mu += __shfl_xor(mu, 8);
        mu *= (1.0f/16.0f);
        const float d = t - mu;
        float v = d*d;
        v += __shfl_xor(v, 1); v += __shfl_xor(v, 2); v += __shfl_xor(v, 4); v += __shfl_xor(v, 8);
        v *= (1.0f/16.0f);
        const float h = gelu_f(d * rsqrtf(v + 1e-5f));
        if (threadIdx.x < 16) hc[j] = h;
    }
    __syncthreads();

    // cv = g*(W_ir@(hc + g*b_ri) + b_ir)
    const float g = 1.0f / (1.0f + expf(-flow_gate[0]));
    if (threadIdx.x < 4) {
        const int l = threadIdx.x;
        float acc = 0.f;
#pragma unroll
        for (int m = 0; m < 16; ++m) acc = fmaf(W_ir[l*16 + m], fmaf(g, b_ri[m], hc[m]), acc);
        cv[l] = g * (acc + b_ir[l]);
    }
    __syncthreads();

    // W_eff[h][j] = sum_l W_o1[h][l] * ((l==j) + g^2 * (W_ir@W_ri)[l][j])
    if (threadIdx.x < 32) {
        const int h = threadIdx.x >> 2, jj = threadIdx.x & 3;
        float we = 0.f;
#pragma unroll
        for (int l = 0; l < 4; ++l) {
            float M = 0.f;
#pragma unroll
            for (int m = 0; m < 16; ++m) M = fmaf(W_ir[l*16 + m], W_ri[m*4 + jj], M);
            const float a2 = ((l == jj) ? 1.0f : 0.0f) + g*g*M;
            we = fmaf(W_o1[h*4 + l], a2, we);
        }
        cst[8 + h*4 + jj] = we;
    }
    // b_eff[h] = b_o1[h] + W_o1[h]@cv
    if (threadIdx.x < 8) {
        const int h = threadIdx.x;
        float be = b_o1[h];
#pragma unroll
        for (int l = 0; l < 4; ++l) be = fmaf(W_o1[h*4 + l], cv[l], be);
        cst[40 + h] = be;
    }
}

// ---------------- pass 2: per-row everything (folded) ----------------
__global__ __launch_bounds__(256) void k_pass2(
    const float* __restrict__ x,
    const float* __restrict__ W_in, const float* __restrict__ b_in,
    const float* __restrict__ r_w,  const float* __restrict__ r_b,
    const float* __restrict__ r_tf,
    const float* __restrict__ W_o2, const float* __restrict__ b_o2,
    const float* __restrict__ cst,
    float* __restrict__ out, int B)
{
    // uniform weights -> registers/SGPRs once per thread
    float w_in[24], bi[4], rw[16], rb[4], tf[32], we[32], be[8], wo2[32], bo2[4];
#pragma unroll
    for (int i = 0; i < 24; ++i) w_in[i] = W_in[i];
#pragma unroll
    for (int i = 0; i < 4; ++i)  bi[i] = b_in[i];
#pragma unroll
    for (int i = 0; i < 16; ++i) rw[i] = r_w[i];
#pragma unroll
    for (int i = 0; i < 4; ++i)  rb[i] = r_b[i];
#pragma unroll
    for (int i = 0; i < 32; ++i) tf[i] = r_tf[i];
#pragma unroll
    for (int i = 0; i < 32; ++i) we[i] = cst[8 + i];
#pragma unroll
    for (int i = 0; i < 8; ++i)  be[i] = cst[40 + i];
#pragma unroll
    for (int i = 0; i < 32; ++i) wo2[i] = W_o2[i];
#pragma unroll
    for (int i = 0; i < 4; ++i)  bo2[i] = b_o2[i];
    const float c0 = cst[0], c1 = cst[1], sr = cst[2];

    const int stride = gridDim.x * blockDim.x;
    for (int i = blockIdx.x * blockDim.x + threadIdx.x; i < B; i += stride) {
        const float2* xp = (const float2*)(x + (size_t)i * 6);
        float2 p0 = xp[0], p1 = xp[1], p2 = xp[2];
        float xv[6] = {p0.x, p0.y, p1.x, p1.y, p2.x, p2.y};

        float xr[4];
#pragma unroll
        for (int j = 0; j < 4; ++j) {
            float a = bi[j];
#pragma unroll
            for (int k = 0; k < 6; ++k) a = fmaf(w_in[j*6+k], xv[k], a);
            xr[j] = gelu_f(a);
        }

        float t[4];
#pragma unroll
        for (int j = 0; j < 4; ++j) {
            float l0 = 0.f, l1 = 0.f, bse = rb[j];
#pragma unroll
            for (int k = 0; k < 4; ++k) {
                l0  = fmaf(tf[j*4+k],      xr[k], l0);
                l1  = fmaf(tf[16 + j*4+k], xr[k], l1);
                bse = fmaf(rw[j*4+k],      xr[k], bse);
            }
            const float corr = __sinf(c0 * l0) * l0 + 0.5f * __sinf(c1 * l1) * l1;
            t[j] = fmaf(sr, corr, bse);
        }

        const float mu = 0.25f * (t[0] + t[1] + t[2] + t[3]);
        float d0 = t[0]-mu, d1 = t[1]-mu, d2 = t[2]-mu, d3 = t[3]-mu;
        const float var = 0.25f * (d0*d0 + d1*d1 + d2*d2 + d3*d3);
        const float inv = rsqrtf(var + 1e-5f);
        float hr[4] = { gelu_f(d0*inv), gelu_f(d1*inv), gelu_f(d2*inv), gelu_f(d3*inv) };

        float hid[8];
#pragma unroll
        for (int h = 0; h < 8; ++h) {
            float a = be[h];
#pragma unroll
            for (int j = 0; j < 4; ++j) a = fmaf(we[h*4+j], hr[j], a);
            hid[h] = gelu_f(a);
        }

        float o[4];
#pragma unroll
        for (int oo = 0; oo < 4; ++oo) {
            float a = bo2[oo];
#pragma unroll
            for (int h = 0; h < 8; ++h) a = fmaf(wo2[oo*8+h], hid[h], a);
            o[oo] = a;
        }
        *(float4*)(out + (size_t)i * 4) = make_float4(o[0], o[1], o[2], o[3]);
    }
}

extern "C" void kernel_launch(void* const* d_in, const int* in_sizes, int n_in,
                              void* d_out, int out_size, void* d_ws, size_t ws_size,
                              hipStream_t stream)
{
    const float* x    = (const float*)d_in[0];
    const float* W_in = (const float*)d_in[1];
    const float* b_in = (const float*)d_in[2];
    const float* r_w  = (const float*)d_in[3];
    const float* r_b  = (const float*)d_in[4];
    const float* r_tf = (const float*)d_in[5];
    const float* r_tc = (const float*)d_in[6];
    const float* i_w  = (const float*)d_in[7];
    const float* i_b  = (const float*)d_in[8];
    const float* i_tf = (const float*)d_in[9];
    const float* i_tc = (const float*)d_in[10];
    const float* W_ri = (const float*)d_in[11];
    const float* b_ri = (const float*)d_in[12];
    const float* W_ir = (const float*)d_in[13];
    const float* b_ir = (const float*)d_in[14];
    const float* fg   = (const float*)d_in[15];
    const float* mem  = (const float*)d_in[16];
    const float* W_o1 = (const float*)d_in[17];
    const float* b_o1 = (const float*)d_in[18];
    const float* W_o2 = (const float*)d_in[19];
    const float* b_o2 = (const float*)d_in[20];
    float* out = (float*)d_out;
    float* ws  = (float*)d_ws;

    const int B = in_sizes[0] / 6;

    // ws layout (floats): [0..47] = constants (cst), [64 .. 64+2*NB1) = block partials
    int NB1 = 2048;
    const long cap = (long)(ws_size / 4) - 64;
    if (cap < 2L * NB1) NB1 = (int)(cap / 2);
    if (NB1 < 1) NB1 = 1;
    float* cst      = ws;
    float* partials = ws + 64;

    k_pass1<<<NB1, 256, 0, stream>>>(x, W_in, b_in, r_tf, partials, B);
    k_mid<<<1, 256, 0, stream>>>(partials, NB1, B, i_w, i_b, i_tf, i_tc,
                                 W_ri, b_ri, W_ir, b_ir, fg, mem, W_o1, b_o1, r_tc, cst);

    int NB2 = (B + 256*4 - 1) / (256*4);
    if (NB2 < 1) NB2 = 1;
    k_pass2<<<NB2, 256, 0, stream>>>(x, W_in, b_in, r_w, r_b, r_tf, W_o2, b_o2, cst, out, B);
}

// Round 2
// 58.007 us; speedup vs baseline: 1.0834x; 1.0834x over previous
//
#include <hip/hip_runtime.h>
#include <math.h>

#define TWO_PI_F 6.2831853071795864769f

// Branchless erf-based exact GELU.
// Abramowitz & Stegun 7.1.26 rational approximation, |err| <= 1.5e-7 over all R,
// saturates correctly as |y|->inf (exp(-y^2)->0). ~17 VALU ops, 2 transcendental.
__device__ __forceinline__ float gelu_f(float v) {
    const float y  = v * 0.70710678118654752f;     // x / sqrt(2)
    const float ay = fabsf(y);
    const float t  = __builtin_amdgcn_rcpf(fmaf(0.3275911f, ay, 1.0f));
    const float e  = __builtin_amdgcn_exp2f(-1.4426950408889634f * y * y); // exp(-y^2)
    float p = fmaf(1.061405429f, t, -1.453152027f);
    p = fmaf(p, t, 1.421413741f);
    p = fmaf(p, t, -0.284496736f);
    p = fmaf(p, t, 0.254829592f);
    const float erf_abs = 1.0f - p * t * e;
    const float erf_v   = copysignf(erf_abs, v);
    const float hv = 0.5f * v;
    return fmaf(hv, erf_v, hv);                    // 0.5*x*(1+erf)
}

// ---------------- pass 1: global sums of |lo_n|; optionally cache xr ----------------
__global__ __launch_bounds__(256) void k_pass1(
    const float* __restrict__ x,
    const float* __restrict__ W_in, const float* __restrict__ b_in,
    const float* __restrict__ r_tf,
    float* __restrict__ partials, float* __restrict__ xr_out, int B)
{
    float w[24], bi[4], tf[32];
#pragma unroll
    for (int i = 0; i < 24; ++i) w[i] = W_in[i];
#pragma unroll
    for (int i = 0; i < 4; ++i) bi[i] = b_in[i];
#pragma unroll
    for (int i = 0; i < 32; ++i) tf[i] = r_tf[i];

    float s0 = 0.f, s1 = 0.f;
    const int np = B >> 1;                         // row pairs
    const int stride = gridDim.x * blockDim.x;
    const bool cache = (xr_out != nullptr);

    for (int p = blockIdx.x * blockDim.x + threadIdx.x; p < np; p += stride) {
        const float4* xp = (const float4*)(x + (size_t)p * 12);
        float4 q0 = xp[0], q1 = xp[1], q2 = xp[2];
        float xv[2][6] = {{q0.x, q0.y, q0.z, q0.w, q1.x, q1.y},
                          {q1.z, q1.w, q2.x, q2.y, q2.z, q2.w}};
        float xr2[2][4];
#pragma unroll
        for (int r = 0; r < 2; ++r) {
#pragma unroll
            for (int j = 0; j < 4; ++j) {
                float a = bi[j];
#pragma unroll
                for (int k = 0; k < 6; ++k) a = fmaf(w[j*6+k], xv[r][k], a);
                xr2[r][j] = gelu_f(a);
            }
#pragma unroll
            for (int j = 0; j < 4; ++j) {
                float l0 = 0.f, l1 = 0.f;
#pragma unroll
                for (int k = 0; k < 4; ++k) {
                    l0 = fmaf(tf[j*4+k],      xr2[r][k], l0);
                    l1 = fmaf(tf[16 + j*4+k], xr2[r][k], l1);
                }
                s0 += fabsf(l0);
                s1 += fabsf(l1);
            }
        }
        if (cache) {
            float4* xo = (float4*)xr_out;
            xo[2*p]   = make_float4(xr2[0][0], xr2[0][1], xr2[0][2], xr2[0][3]);
            xo[2*p+1] = make_float4(xr2[1][0], xr2[1][1], xr2[1][2], xr2[1][3]);
        }
    }

    // odd tail row (B is 2M in practice; keep correct anyway)
    if ((B & 1) && blockIdx.x == 0 && threadIdx.x == 0) {
        const int i = B - 1;
        const float* xs = x + (size_t)i * 6;
        float xv[6];
#pragma unroll
        for (int k = 0; k < 6; ++k) xv[k] = xs[k];
        float xr[4];
#pragma unroll
        for (int j = 0; j < 4; ++j) {
            float a = bi[j];
#pragma unroll
            for (int k = 0; k < 6; ++k) a = fmaf(w[j*6+k], xv[k], a);
            xr[j] = gelu_f(a);
        }
#pragma unroll
        for (int j = 0; j < 4; ++j) {
            float l0 = 0.f, l1 = 0.f;
#pragma unroll
            for (int k = 0; k < 4; ++k) {
                l0 = fmaf(tf[j*4+k],      xr[k], l0);
                l1 = fmaf(tf[16 + j*4+k], xr[k], l1);
            }
            s0 += fabsf(l0);
            s1 += fabsf(l1);
        }
        if (cache) {
            float* xo = xr_out + (size_t)i * 4;
#pragma unroll
            for (int j = 0; j < 4; ++j) xo[j] = xr[j];
        }
    }

#pragma unroll
    for (int off = 32; off > 0; off >>= 1) {
        s0 += __shfl_down(s0, off);
        s1 += __shfl_down(s1, off);
    }
    __shared__ float sm[8];
    const int wid = threadIdx.x >> 6;
    if ((threadIdx.x & 63) == 0) { sm[wid*2] = s0; sm[wid*2+1] = s1; }
    __syncthreads();
    if (threadIdx.x == 0) {
        float t0 = 0.f, t1 = 0.f;
        const int nw = (int)(blockDim.x >> 6);
        for (int k2 = 0; k2 < nw; ++k2) { t0 += sm[k2*2]; t1 += sm[k2*2+1]; }
        partials[(size_t)blockIdx.x * 2]     = t0;
        partials[(size_t)blockIdx.x * 2 + 1] = t1;
    }
}

// ---------------- mid: finalize sums; fold internal path into W_eff/b_eff ----------
// cst layout (floats): [0]=c0 [1]=c1 [2]=sr  [8..39]=W_eff(8x4) [40..47]=b_eff(8)
__global__ __launch_bounds__(256) void k_mid(
    const float* __restrict__ partials, int nb, int B,
    const float* __restrict__ i_w,  const float* __restrict__ i_b,
    const float* __restrict__ i_tf, const float* __restrict__ i_tc,
    const float* __restrict__ W_ri, const float* __restrict__ b_ri,
    const float* __restrict__ W_ir, const float* __restrict__ b_ir,
    const float* __restrict__ flow_gate, const float* __restrict__ mem,
    const float* __restrict__ W_o1, const float* __restrict__ b_o1,
    const float* __restrict__ r_tc,
    float* __restrict__ cst)
{
    __shared__ float red[8];
    __shared__ float hc[16];
    __shared__ float cv[4];

    float s0 = 0.f, s1 = 0.f;
    for (int k = threadIdx.x; k < nb; k += blockDim.x) {
        s0 += partials[(size_t)k*2];
        s1 += partials[(size_t)k*2 + 1];
    }
#pragma unroll
    for (int off = 32; off > 0; off >>= 1) { s0 += __shfl_down(s0, off); s1 += __shfl_down(s1, off); }
    const int wid = threadIdx.x >> 6;
    if ((threadIdx.x & 63) == 0) { red[wid*2] = s0; red[wid*2+1] = s1; }
    __syncthreads();
    if (threadIdx.x == 0) {
        float t0 = 0.f, t1 = 0.f;
        for (int k2 = 0; k2 < 4; ++k2) { t0 += red[k2*2]; t1 += red[k2*2+1]; }
        const float m0 = t0 / (4.0f * (float)B);
        const float m1 = t1 / (4.0f * (float)B);
        cst[0] = TWO_PI_F * 1.0f / (m0 + 1e-8f);
        cst[1] = TWO_PI_F * 2.0f / (m1 + 1e-8f);
        cst[2] = 1.0f / (1.0f + expf(-r_tc[0]));
    }

    if (threadIdx.x < 64) {
        const int j = threadIdx.x & 15;
        float base = i_b[j];
#pragma unroll
        for (int k = 0; k < 16; ++k) base = fmaf(i_w[j*16 + k], mem[k], base);
        float corr = 0.f;
#pragma unroll
        for (int n = 0; n < 3; ++n) {
            float lo = 0.f;
#pragma unroll
            for (int k = 0; k < 16; ++k) lo = fmaf(i_tf[n*256 + j*16 + k], mem[k], lo);
            float a = fabsf(lo);
            a += __shfl_xor(a, 1); a += __shfl_xor(a, 2); a += __shfl_xor(a, 4); a += __shfl_xor(a, 8);
            const float mean = a * (1.0f/16.0f);
            const float phase = TWO_PI_F * (float)(n+1) * lo / (mean + 1e-8f);
            corr = fmaf(sinf(phase), lo / (float)(n+1), corr);
        }
        const float sc = 1.0f / (1.0f + expf(-i_tc[0]));
        const float t = fmaf(sc, corr, base);
        float mu = t;
        mu += __shfl_xor(mu, 1); mu += __shfl_xor(mu, 2); mu += __shfl_xor(mu, 4); mu += __shfl_xor(mu, 8);
        mu *= (1.0f/16.0f);
        const float d = t - mu;
        float v = d*d;
        v += __shfl_xor(v, 1); v += __shfl_xor(v, 2); v += __shfl_xor(v, 4); v += __shfl_xor(v, 8);
        v *= (1.0f/16.0f);
        const float h = gelu_f(d * rsqrtf(v + 1e-5f));
        if (threadIdx.x < 16) hc[j] = h;
    }
    __syncthreads();

    const float g = 1.0f / (1.0f + expf(-flow_gate[0]));
    if (threadIdx.x < 4) {
        const int l = threadIdx.x;
        float acc = 0.f;
#pragma unroll
        for (int m = 0; m < 16; ++m) acc = fmaf(W_ir[l*16 + m], fmaf(g, b_ri[m], hc[m]), acc);
        cv[l] = g * (acc + b_ir[l]);
    }
    __syncthreads();

    if (threadIdx.x < 32) {
        const int h = threadIdx.x >> 2, jj = threadIdx.x & 3;
        float we = 0.f;
#pragma unroll
        for (int l = 0; l < 4; ++l) {
            float M = 0.f;
#pragma unroll
            for (int m = 0; m < 16; ++m) M = fmaf(W_ir[l*16 + m], W_ri[m*4 + jj], M);
            const float a2 = ((l == jj) ? 1.0f : 0.0f) + g*g*M;
            we = fmaf(W_o1[h*4 + l], a2, we);
        }
        cst[8 + h*4 + jj] = we;
    }
    if (threadIdx.x < 8) {
        const int h = threadIdx.x;
        float be = b_o1[h];
#pragma unroll
        for (int l = 0; l < 4; ++l) be = fmaf(W_o1[h*4 + l], cv[l], be);
        cst[40 + h] = be;
    }
}

// ---------------- shared per-row tail: torsion -> LN -> gelu -> folded MLP ----------
__device__ __forceinline__ void row_tail(
    const float xr[4], const float* __restrict__ rw, const float* __restrict__ rb,
    const float* __restrict__ tf, const float* __restrict__ we, const float* __restrict__ be,
    const float* __restrict__ wo2, const float* __restrict__ bo2,
    float c0, float c1, float sr, float o[4])
{
    float t[4];
#pragma unroll
    for (int j = 0; j < 4; ++j) {
        float l0 = 0.f, l1 = 0.f, bse = rb[j];
#pragma unroll
        for (int k = 0; k < 4; ++k) {
            l0  = fmaf(tf[j*4+k],      xr[k], l0);
            l1  = fmaf(tf[16 + j*4+k], xr[k], l1);
            bse = fmaf(rw[j*4+k],      xr[k], bse);
        }
        const float corr = __sinf(c0 * l0) * l0 + 0.5f * __sinf(c1 * l1) * l1;
        t[j] = fmaf(sr, corr, bse);
    }

    const float mu = 0.25f * (t[0] + t[1] + t[2] + t[3]);
    float d0 = t[0]-mu, d1 = t[1]-mu, d2 = t[2]-mu, d3 = t[3]-mu;
    const float var = 0.25f * (d0*d0 + d1*d1 + d2*d2 + d3*d3);
    const float inv = rsqrtf(var + 1e-5f);
    float hr[4] = { gelu_f(d0*inv), gelu_f(d1*inv), gelu_f(d2*inv), gelu_f(d3*inv) };

    float hid[8];
#pragma unroll
    for (int h = 0; h < 8; ++h) {
        float a = be[h];
#pragma unroll
        for (int j = 0; j < 4; ++j) a = fmaf(we[h*4+j], hr[j], a);
        hid[h] = gelu_f(a);
    }
#pragma unroll
    for (int oo = 0; oo < 4; ++oo) {
        float a = bo2[oo];
#pragma unroll
        for (int h = 0; h < 8; ++h) a = fmaf(wo2[oo*8+h], hid[h], a);
        o[oo] = a;
    }
}

// ---------------- pass 2 (cached xr): 1 float4 in, 1 float4 out per row -------------
__global__ __launch_bounds__(256) void k_pass2c(
    const float* __restrict__ xr_in,
    const float* __restrict__ r_w,  const float* __restrict__ r_b,
    const float* __restrict__ r_tf,
    const float* __restrict__ W_o2, const float* __restrict__ b_o2,
    const float* __restrict__ cst,
    float* __restrict__ out, int B)
{
    float rw[16], rb[4], tf[32], we[32], be[8], wo2[32], bo2[4];
#pragma unroll
    for (int i = 0; i < 16; ++i) rw[i] = r_w[i];
#pragma unroll
    for (int i = 0; i < 4; ++i)  rb[i] = r_b[i];
#pragma unroll
    for (int i = 0; i < 32; ++i) tf[i] = r_tf[i];
#pragma unroll
    for (int i = 0; i < 32; ++i) we[i] = cst[8 + i];
#pragma unroll
    for (int i = 0; i < 8; ++i)  be[i] = cst[40 + i];
#pragma unroll
    for (int i = 0; i < 32; ++i) wo2[i] = W_o2[i];
#pragma unroll
    for (int i = 0; i < 4; ++i)  bo2[i] = b_o2[i];
    const float c0 = cst[0], c1 = cst[1], sr = cst[2];

    const int stride = gridDim.x * blockDim.x;
    for (int i = blockIdx.x * blockDim.x + threadIdx.x; i < B; i += stride) {
        const float4 q = ((const float4*)xr_in)[i];
        float xr[4] = {q.x, q.y, q.z, q.w};
        float o[4];
        row_tail(xr, rw, rb, tf, we, be, wo2, bo2, c0, c1, sr, o);
        ((float4*)out)[i] = make_float4(o[0], o[1], o[2], o[3]);
    }
}

// ---------------- pass 2 fallback (recompute xr from x) -----------------------------
__global__ __launch_bounds__(256) void k_pass2(
    const float* __restrict__ x,
    const float* __restrict__ W_in, const float* __restrict__ b_in,
    const float* __restrict__ r_w,  const float* __restrict__ r_b,
    const float* __restrict__ r_tf,
    const float* __restrict__ W_o2, const float* __restrict__ b_o2,
    const float* __restrict__ cst,
    float* __restrict__ out, int B)
{
    float w_in[24], bi[4], rw[16], rb[4], tf[32], we[32], be[8], wo2[32], bo2[4];
#pragma unroll
    for (int i = 0; i < 24; ++i) w_in[i] = W_in[i];
#pragma unroll
    for (int i = 0; i < 4; ++i)  bi[i] = b_in[i];
#pragma unroll
    for (int i = 0; i < 16; ++i) rw[i] = r_w[i];
#pragma unroll
    for (int i = 0; i < 4; ++i)  rb[i] = r_b[i];
#pragma unroll
    for (int i = 0; i < 32; ++i) tf[i] = r_tf[i];
#pragma unroll
    for (int i = 0; i < 32; ++i) we[i] = cst[8 + i];
#pragma unroll
    for (int i = 0; i < 8; ++i)  be[i] = cst[40 + i];
#pragma unroll
    for (int i = 0; i < 32; ++i) wo2[i] = W_o2[i];
#pragma unroll
    for (int i = 0; i < 4; ++i)  bo2[i] = b_o2[i];
    const float c0 = cst[0], c1 = cst[1], sr = cst[2];

    const int stride = gridDim.x * blockDim.x;
    for (int i = blockIdx.x * blockDim.x + threadIdx.x; i < B; i += stride) {
        const float2* xp = (const float2*)(x + (size_t)i * 6);
        float2 p0 = xp[0], p1 = xp[1], p2 = xp[2];
        float xv[6] = {p0.x, p0.y, p1.x, p1.y, p2.x, p2.y};
        float xr[4];
#pragma unroll
        for (int j = 0; j < 4; ++j) {
            float a = bi[j];
#pragma unroll
            for (int k = 0; k < 6; ++k) a = fmaf(w_in[j*6+k], xv[k], a);
            xr[j] = gelu_f(a);
        }
        float o[4];
        row_tail(xr, rw, rb, tf, we, be, wo2, bo2, c0, c1, sr, o);
        ((float4*)out)[i] = make_float4(o[0], o[1], o[2], o[3]);
    }
}

extern "C" void kernel_launch(void* const* d_in, const int* in_sizes, int n_in,
                              void* d_out, int out_size, void* d_ws, size_t ws_size,
                              hipStream_t stream)
{
    const float* x    = (const float*)d_in[0];
    const float* W_in = (const float*)d_in[1];
    const float* b_in = (const float*)d_in[2];
    const float* r_w  = (const float*)d_in[3];
    const float* r_b  = (const float*)d_in[4];
    const float* r_tf = (const float*)d_in[5];
    const float* r_tc = (const float*)d_in[6];
    const float* i_w  = (const float*)d_in[7];
    const float* i_b  = (const float*)d_in[8];
    const float* i_tf = (const float*)d_in[9];
    const float* i_tc = (const float*)d_in[10];
    const float* W_ri = (const float*)d_in[11];
    const float* b_ri = (const float*)d_in[12];
    const float* W_ir = (const float*)d_in[13];
    const float* b_ir = (const float*)d_in[14];
    const float* fg   = (const float*)d_in[15];
    const float* mem  = (const float*)d_in[16];
    const float* W_o1 = (const float*)d_in[17];
    const float* b_o1 = (const float*)d_in[18];
    const float* W_o2 = (const float*)d_in[19];
    const float* b_o2 = (const float*)d_in[20];
    float* out = (float*)d_out;
    float* ws  = (float*)d_ws;

    const int B = in_sizes[0] / 6;

    // ws layout (floats): [0..63]=cst, [64..64+2*NB1)=partials, [8192..8192+4B)=xr cache
    int NB1 = 2048;
    const long cap = (long)(ws_size / 4) - 64;
    if (cap < 2L * NB1) NB1 = (int)(cap / 2);
    if (NB1 < 1) NB1 = 1;
    float* cst      = ws;
    float* partials = ws + 64;

    const size_t need = ((size_t)8192 + 4ull * (size_t)B) * 4ull;
    const bool cached = (ws_size >= need) && (NB1 == 2048);
    float* xr = ws + 8192;

    k_pass1<<<NB1, 256, 0, stream>>>(x, W_in, b_in, r_tf, partials,
                                     cached ? xr : nullptr, B);
    k_mid<<<1, 256, 0, stream>>>(partials, NB1, B, i_w, i_b, i_tf, i_tc,
                                 W_ri, b_ri, W_ir, b_ir, fg, mem, W_o1, b_o1, r_tc, cst);

    int NB2 = (B + 256*4 - 1) / (256*4);
    if (NB2 < 1) NB2 = 1;
    if (cached) {
        k_pass2c<<<NB2, 256, 0, stream>>>(xr, r_w, r_b, r_tf, W_o2, b_o2, cst, out, B);
    } else {
        k_pass2<<<NB2, 256, 0, stream>>>(x, W_in, b_in, r_w, r_b, r_tf, W_o2, b_o2,
                                         cst, out, B);
    }
}